// Round 4
// baseline (609.529 us; speedup 1.0000x reference)
//
#include <hip/hip_runtime.h>
#include <cstdint>
#include <cstddef>

typedef unsigned short u16;
typedef __attribute__((ext_vector_type(8))) short bf16x8;
typedef __attribute__((ext_vector_type(4))) float f32x4;

#define MFMA32(a, b, c) __builtin_amdgcn_mfma_f32_16x16x32_bf16(a, b, c, 0, 0, 0)

__device__ __forceinline__ u16 f2b(float f) {
  union { float f; unsigned u; } v; v.f = f;
  unsigned u = v.u;
  return (u16)((u + 0x7fffu + ((u >> 16) & 1u)) >> 16);
}
__device__ __forceinline__ float b2f(u16 h) {
  union { unsigned u; float f; } v; v.u = ((unsigned)h) << 16;
  return v.f;
}

// async global->LDS, 16B per lane. LDS dest must be wave-uniform base + lane*16.
__device__ __forceinline__ void g2l16(const void* g, void* l) {
  __builtin_amdgcn_global_load_lds((__attribute__((address_space(1))) void*)(g),
                                   (__attribute__((address_space(3))) void*)(l), 16, 0, 0);
}

// ---------------- fp32 -> bf16 cast (vectorized x4) ----------------
__global__ __launch_bounds__(256) void cast_f2b_v4(const float* __restrict__ in,
                                                   u16* __restrict__ out, int n4) {
  int i = blockIdx.x * 256 + threadIdx.x;
  if (i >= n4) return;
  float4 v = ((const float4*)in)[i];
  ushort4 r;
  r.x = f2b(v.x); r.y = f2b(v.y); r.z = f2b(v.z); r.w = f2b(v.w);
  ((ushort4*)out)[i] = r;
}

// ---------------- C = A @ B^T   (A: MxK bf16, B: NxK bf16, both K-major) ------
// 128x128 tile, BK=64, 4 waves (2x2), 4x4 MFMA/wave. XOR-chunk-swizzled LDS.
// (Proven structure; the 256² 8-phase port regressed 2x in R2 — reverted.)
template <bool BF16_OUT>
__global__ __launch_bounds__(256) void gemm_bt(const u16* __restrict__ A,
                                               const u16* __restrict__ B,
                                               void* __restrict__ C, int N, int K) {
  __shared__ u16 As[128 * 64];
  __shared__ u16 Bs[128 * 64];
  const int tid = threadIdx.x;
  const int wid = tid >> 6;
  const int lane = tid & 63;
  const int lm = lane & 15;
  const int quad = lane >> 4;
  const int r3 = lm & 7;
  const int wm = (wid & 1) * 64;
  const int wn = (wid >> 1) * 64;
  const int bm = blockIdx.y * 128;
  const int bn = blockIdx.x * 128;

  const u16* Ab = A + (size_t)bm * K;
  const u16* Bb = B + (size_t)bn * K;

  f32x4 zero = {0.f, 0.f, 0.f, 0.f};
  f32x4 acc[4][4];
#pragma unroll
  for (int i = 0; i < 4; ++i)
#pragma unroll
    for (int j = 0; j < 4; ++j) acc[i][j] = zero;

  for (int k0 = 0; k0 < K; k0 += 64) {
#pragma unroll
    for (int it = 0; it < 4; ++it) {
      int c = it * 256 + tid;
      int rg = c >> 6, rw = (c >> 3) & 7, u = c & 7;
      int row = rg * 8 + rw;
      int chd = u ^ rw;  // store chunk (row, chd) at linear chunk c
      g2l16(Ab + (size_t)row * K + k0 + chd * 8, As + c * 8);
      g2l16(Bb + (size_t)row * K + k0 + chd * 8, Bs + c * 8);
    }
    __syncthreads();
#pragma unroll
    for (int ks = 0; ks < 2; ++ks) {
      bf16x8 a[4], b[4];
      int chd = ks * 4 + quad;
#pragma unroll
      for (int i = 0; i < 4; ++i) {
        int row = wm + i * 16 + lm;  // row&7 == r3
        a[i] = *(const bf16x8*)(As + (((row >> 3) * 64 + r3 * 8 + (chd ^ r3)) * 8));
      }
#pragma unroll
      for (int j = 0; j < 4; ++j) {
        int row = wn + j * 16 + lm;
        b[j] = *(const bf16x8*)(Bs + (((row >> 3) * 64 + r3 * 8 + (chd ^ r3)) * 8));
      }
#pragma unroll
      for (int i = 0; i < 4; ++i)
#pragma unroll
        for (int j = 0; j < 4; ++j)
          acc[i][j] = MFMA32(a[i], b[j], acc[i][j]);
    }
    __syncthreads();
  }

#pragma unroll
  for (int i = 0; i < 4; ++i)
#pragma unroll
    for (int j = 0; j < 4; ++j)
#pragma unroll
      for (int r = 0; r < 4; ++r) {
        int row = bm + wm + i * 16 + quad * 4 + r;
        int col = bn + wn + j * 16 + lm;
        float v = acc[i][j][r];
        if (BF16_OUT)
          ((u16*)C)[(size_t)row * N + col] = f2b(v);
        else
          ((float*)C)[(size_t)row * N + col] = v;
      }
}

// ---------------- RoPE + head rearrange v2: coalesced VT via LDS transpose ----
__global__ __launch_bounds__(256) void rope_rearrange_v2(const u16* __restrict__ Y,
                                                         u16* __restrict__ Q,
                                                         u16* __restrict__ Kb,
                                                         u16* __restrict__ VT) {
  const float SC = 0.12751744f;  // (1/sqrt(128)) * log2(e)
  __shared__ u16 T[128][68];     // V tile: [d][s_local], padded stride
  const int st = blockIdx.x;     // s-tile (64 rows)
  const int bh = blockIdx.y;     // b*16 + h
  const int b = bh >> 4, h = bh & 15;
  const int tid = threadIdx.x;
  const int d = tid & 127;
  const int sgrp = tid >> 7;  // 0/1

  // hoisted rope frequency (depends only on d)
  float inv = 0.f;
  const int f0 = d & 31;
  if (d >= 64) inv = __powf(10000.0f, -(float)(2 * f0) * (1.0f / 64.0f));

  const u16* Yc = Y + (size_t)(b * 2048 + st * 64) * 6144;

#pragma unroll 4
  for (int k = 0; k < 32; ++k) {
    const int sl = sgrp * 32 + k;
    const int s = st * 64 + sl;
    const u16* Yr = Yc + (size_t)sl * 6144;

    // V -> LDS tile (global read coalesced along d)
    T[d][sl] = Yr[4096 + h * 128 + d];

    float qv, kv;
    if (d < 64) {
      qv = b2f(Yr[h * 64 + d]);
      kv = b2f(Yr[1024 + h * 64 + d]);
    } else {
      float ang = (float)s * inv;
      float sn = sinf(ang), cs = cosf(ang);
      float qx1 = b2f(Yr[2048 + h * 64 + f0]);
      float qx2 = b2f(Yr[2048 + h * 64 + f0 + 32]);
      float kx1 = b2f(Yr[3072 + h * 64 + f0]);
      float kx2 = b2f(Yr[3072 + h * 64 + f0 + 32]);
      if (d < 96) { qv = qx1 * cs - qx2 * sn; kv = kx1 * cs - kx2 * sn; }
      else        { qv = qx1 * sn + qx2 * cs; kv = kx1 * sn + kx2 * cs; }
    }
    size_t qo = ((size_t)bh * 2048 + s) * 128 + d;
    Q[qo] = f2b(qv * SC);
    Kb[qo] = f2b(kv);
  }
  __syncthreads();

  // VT write: row dd gets 64 consecutive s (128B), as ushort4 (8B/lane, coalesced)
#pragma unroll
  for (int it = 0; it < 8; ++it) {
    const int i = it * 256 + tid;
    const int dd = i >> 4;      // 0..127
    const int ch = i & 15;      // 16 x ushort4 per row
    ushort4 v = *(const ushort4*)(&T[dd][ch * 4]);
    *(ushort4*)(VT + ((size_t)bh * 128 + dd) * 2048 + st * 64 + ch * 4) = v;
  }
}

// ---------------- fused causal attention v6: barrier-free, direct-global K/V --
// K/V are L2-resident (16 blocks share each bh's 1MB K+VT slice) and each
// fragment re-read is L1-resident, so LDS staging was pure overhead (m169).
// Fragment loads are sector-efficient: per (ks,j) instruction, 64 lanes read
// 16 rows x 64 contiguous bytes. Ps is WAVE-PRIVATE (each wave writes and
// reads only rows wrow..wrow+15) -> with Ks/Vs gone there is no shared state
// and the kt loop needs NO __syncthreads at all: each wave is an independent
// load->MFMA pipeline (compiler emits counted vmcnt waits), 8 waves/CU overlap.
__global__ __launch_bounds__(256, 2) void attn_v6(const u16* __restrict__ Q,
                                                  const u16* __restrict__ K,
                                                  const u16* __restrict__ VT,
                                                  u16* __restrict__ O) {
  constexpr int S = 2048;
  constexpr int D = 128;
  __shared__ u16 Ps[64 * 72];   // per-wave 16 rows each; padded stride 72
  const int bx = blockIdx.x;
  const int bh = blockIdx.y;
  const int b = bh >> 4, h = bh & 15;
  const int tid = threadIdx.x, wid = tid >> 6, lane = tid & 63;
  const int lm = lane & 15, quad = lane >> 4;
  const int wrow = wid * 16;

  const u16* Kbh = K + (size_t)bh * S * D;
  const u16* Vbh = VT + (size_t)bh * D * S;

#pragma unroll 1
  for (int pass = 0; pass < 2; ++pass) {
    const int qt = pass == 0 ? bx : 31 - bx;

    // Q A-operand fragments direct from global
    bf16x8 aq[4];
#pragma unroll
    for (int ks = 0; ks < 4; ++ks)
      aq[ks] = *(const bf16x8*)(Q + ((size_t)bh * S + (size_t)qt * 64 + wrow + lm) * D +
                                ks * 32 + quad * 8);

    float l_r[4] = {0.f, 0.f, 0.f, 0.f};
    f32x4 zero = {0.f, 0.f, 0.f, 0.f};
    f32x4 oacc[8];
#pragma unroll
    for (int t = 0; t < 8; ++t) oacc[t] = zero;

#pragma unroll 1
    for (int kt = 0; kt <= qt; ++kt) {
      const u16* Kt = Kbh + (size_t)kt * 64 * D;
      const u16* Vt = Vbh + (size_t)kt * 64;

      // S-tile = Q K^T : wave rows wrow..wrow+15, 64 cols; K direct from global
      f32x4 sc[4];
#pragma unroll
      for (int j = 0; j < 4; ++j) sc[j] = zero;
      __builtin_amdgcn_s_setprio(1);
#pragma unroll
      for (int ks = 0; ks < 4; ++ks) {
#pragma unroll
        for (int j = 0; j < 4; ++j) {
          bf16x8 bk = *(const bf16x8*)(Kt + (j * 16 + lm) * D + ks * 32 + quad * 8);
          sc[j] = MFMA32(aq[ks], bk, sc[j]);
        }
      }
      __builtin_amdgcn_s_setprio(0);

      const bool diag = (kt == qt);
#pragma unroll
      for (int r = 0; r < 4; ++r) {
        const int qcol = wrow + quad * 4 + r;  // q row within this 64-tile
        float pv[4];
        float rs = 0.f;
#pragma unroll
        for (int j = 0; j < 4; ++j) {
          float p = __builtin_amdgcn_exp2f(fminf(sc[j][r], 30.0f));
          if (diag && (j * 16 + lm > qcol)) p = 0.f;
          rs += p;
          pv[j] = p;
        }
#pragma unroll
        for (int dd = 1; dd < 16; dd <<= 1) rs += __shfl_xor(rs, dd);
        l_r[r] += rs;
        const int prow = (wrow + quad * 4 + r) * 72;
#pragma unroll
        for (int j = 0; j < 4; ++j) Ps[prow + j * 16 + lm] = f2b(pv[j]);
      }
      // no barrier: Ps rows are wave-private; compiler orders via lgkmcnt

      // O += P @ V : P (16x64 own rows, stride 72) as A, VT rows direct as B
      __builtin_amdgcn_s_setprio(1);
#pragma unroll
      for (int ks = 0; ks < 2; ++ks) {
        bf16x8 ap = *(const bf16x8*)(Ps + (wrow + lm) * 72 + ks * 32 + quad * 8);
#pragma unroll
        for (int t = 0; t < 8; ++t) {
          bf16x8 bv = *(const bf16x8*)(Vt + (size_t)(t * 16 + lm) * S + ks * 32 + quad * 8);
          oacc[t] = MFMA32(ap, bv, oacc[t]);
        }
      }
      __builtin_amdgcn_s_setprio(0);
    }

    // epilogue: O row = b*S + s, col = h*128 + d  (bf16)
#pragma unroll
    for (int r = 0; r < 4; ++r) {
      float inv = 1.0f / l_r[r];
      const int srow = qt * 64 + wrow + quad * 4 + r;
      u16* Orow = O + ((size_t)b * S + srow) * 2048 + h * 128;
#pragma unroll
      for (int t = 0; t < 8; ++t) Orow[t * 16 + lm] = f2b(oacc[t][r] * inv);
    }
  }
}

extern "C" void kernel_launch(void* const* d_in, const int* in_sizes, int n_in,
                              void* d_out, int out_size, void* d_ws, size_t ws_size,
                              hipStream_t stream) {
  const float* x      = (const float*)d_in[0];
  const float* Wq_sem = (const float*)d_in[1];
  const float* Wk_sem = (const float*)d_in[2];
  const float* Wq_geo = (const float*)d_in[3];
  const float* Wk_geo = (const float*)d_in[4];
  const float* Wv     = (const float*)d_in[5];
  const float* Wo     = (const float*)d_in[6];

  char* ws = (char*)d_ws;
  // layout (bytes):
  //   [0, 16M)          xb  (x bf16, 4096x2048)        -> later reused as Q
  //   [16M, 41.2M)      Wall (6144x2048 bf16)          -> later reused as O
  //   [41.2M, 49.6M)    Wob  (2048x2048 bf16)
  //   [49.6M, 99.9M)    Y    (4096x6144 bf16)
  // d_out (33.5MB) used as scratch for K (16.7M) + VT (16.7M) until final GEMM.
  u16* xb   = (u16*)(ws);
  u16* Wall = (u16*)(ws + 16777216);
  u16* Wob  = (u16*)(ws + 16777216 + 25165824);
  u16* Y    = (u16*)(ws + 16777216 + 25165824 + 8388608);
  u16* Qb   = xb;
  u16* Ob   = Wall;
  u16* Kb   = (u16*)d_out;
  u16* VT   = (u16*)((char*)d_out + 16777216);

  // casts to bf16
  cast_f2b_v4<<<8192, 256, 0, stream>>>(x, xb, 2097152);
  cast_f2b_v4<<<2048, 256, 0, stream>>>(Wq_sem, Wall + 0 * 2097152, 524288);
  cast_f2b_v4<<<2048, 256, 0, stream>>>(Wk_sem, Wall + 1 * 2097152, 524288);
  cast_f2b_v4<<<2048, 256, 0, stream>>>(Wq_geo, Wall + 2 * 2097152, 524288);
  cast_f2b_v4<<<2048, 256, 0, stream>>>(Wk_geo, Wall + 3 * 2097152, 524288);
  cast_f2b_v4<<<4096, 256, 0, stream>>>(Wv,     Wall + 4 * 2097152, 1048576);
  cast_f2b_v4<<<4096, 256, 0, stream>>>(Wo, Wob, 1048576);

  // fused QKV projection: Y = x @ Wall^T   (M=4096, N=6144, K=2048)
  gemm_bt<true><<<dim3(48, 32), 256, 0, stream>>>(xb, Wall, Y, 6144, 2048);

  // RoPE + head split/rearrange (Q pre-scaled by 1/sqrt(128)*log2e)
  rope_rearrange_v2<<<dim3(32, 32), 256, 0, stream>>>(Y, Qb, Kb, VT);

  // causal flash attention -> O (B*S, 2048) bf16
  attn_v6<<<dim3(16, 32), 256, 0, stream>>>(Qb, Kb, VT, Ob);

  // final projection: out = O @ Wo^T  (M=4096, N=2048, K=2048), fp32 out
  gemm_bt<false><<<dim3(16, 32), 256, 0, stream>>>(Ob, Wob, d_out, 2048, 2048);
}

// Round 5
// 415.208 us; speedup vs baseline: 1.4680x; 1.4680x over previous
//
#include <hip/hip_runtime.h>
#include <cstdint>
#include <cstddef>

typedef unsigned short u16;
typedef __attribute__((ext_vector_type(8))) short bf16x8;
typedef __attribute__((ext_vector_type(4))) float f32x4;

#define MFMA32(a, b, c) __builtin_amdgcn_mfma_f32_16x16x32_bf16(a, b, c, 0, 0, 0)

__device__ __forceinline__ u16 f2b(float f) {
  union { float f; unsigned u; } v; v.f = f;
  unsigned u = v.u;
  return (u16)((u + 0x7fffu + ((u >> 16) & 1u)) >> 16);
}
__device__ __forceinline__ float b2f(u16 h) {
  union { unsigned u; float f; } v; v.u = ((unsigned)h) << 16;
  return v.f;
}

// async global->LDS, 16B per lane. LDS dest must be wave-uniform base + lane*16.
__device__ __forceinline__ void g2l16(const void* g, void* l) {
  __builtin_amdgcn_global_load_lds((__attribute__((address_space(1))) void*)(g),
                                   (__attribute__((address_space(3))) void*)(l), 16, 0, 0);
}

// ---------------- fp32 -> bf16 cast (vectorized x4) ----------------
__global__ __launch_bounds__(256) void cast_f2b_v4(const float* __restrict__ in,
                                                   u16* __restrict__ out, int n4) {
  int i = blockIdx.x * 256 + threadIdx.x;
  if (i >= n4) return;
  float4 v = ((const float4*)in)[i];
  ushort4 r;
  r.x = f2b(v.x); r.y = f2b(v.y); r.z = f2b(v.z); r.w = f2b(v.w);
  ((ushort4*)out)[i] = r;
}

// ---------------- all weight casts in ONE launch (cuts 5 dispatch gaps) -------
// blocks 0..8191: Wq_sem/Wk_sem/Wq_geo/Wk_geo (2048 blocks each) -> Wall[s]
// blocks 8192..12287: Wv -> Wall[4]; blocks 12288..16383: Wo -> Wob
__global__ __launch_bounds__(256) void cast_weights(const float* __restrict__ W0,
                                                    const float* __restrict__ W1,
                                                    const float* __restrict__ W2,
                                                    const float* __restrict__ W3,
                                                    const float* __restrict__ Wv,
                                                    const float* __restrict__ Wo,
                                                    u16* __restrict__ Wall,
                                                    u16* __restrict__ Wob) {
  const int blk = blockIdx.x;
  const float* src;
  u16* dst;
  int li;
  if (blk < 8192) {
    const int s = blk >> 11;  // uniform per block
    src = s == 0 ? W0 : s == 1 ? W1 : s == 2 ? W2 : W3;
    dst = Wall + (size_t)s * 2097152;
    li = (blk & 2047) * 256 + threadIdx.x;
  } else if (blk < 12288) {
    src = Wv;
    dst = Wall + (size_t)4 * 2097152;
    li = (blk - 8192) * 256 + threadIdx.x;
  } else {
    src = Wo;
    dst = Wob;
    li = (blk - 12288) * 256 + threadIdx.x;
  }
  float4 v = ((const float4*)src)[li];
  ushort4 r;
  r.x = f2b(v.x); r.y = f2b(v.y); r.z = f2b(v.z); r.w = f2b(v.w);
  ((ushort4*)dst)[li] = r;
}

// ---------------- C = A @ B^T   (A: MxK bf16, B: NxK bf16, both K-major) ------
// 128x128 tile, BK=64, 4 waves (2x2), 4x4 MFMA/wave. XOR-chunk-swizzled LDS.
template <bool BF16_OUT>
__global__ __launch_bounds__(256) void gemm_bt(const u16* __restrict__ A,
                                               const u16* __restrict__ B,
                                               void* __restrict__ C, int N, int K) {
  __shared__ u16 As[128 * 64];
  __shared__ u16 Bs[128 * 64];
  const int tid = threadIdx.x;
  const int wid = tid >> 6;
  const int lane = tid & 63;
  const int lm = lane & 15;
  const int quad = lane >> 4;
  const int r3 = lm & 7;
  const int wm = (wid & 1) * 64;
  const int wn = (wid >> 1) * 64;
  const int bm = blockIdx.y * 128;
  const int bn = blockIdx.x * 128;

  const u16* Ab = A + (size_t)bm * K;
  const u16* Bb = B + (size_t)bn * K;

  f32x4 zero = {0.f, 0.f, 0.f, 0.f};
  f32x4 acc[4][4];
#pragma unroll
  for (int i = 0; i < 4; ++i)
#pragma unroll
    for (int j = 0; j < 4; ++j) acc[i][j] = zero;

  for (int k0 = 0; k0 < K; k0 += 64) {
#pragma unroll
    for (int it = 0; it < 4; ++it) {
      int c = it * 256 + tid;
      int rg = c >> 6, rw = (c >> 3) & 7, u = c & 7;
      int row = rg * 8 + rw;
      int chd = u ^ rw;  // store chunk (row, chd) at linear chunk c
      g2l16(Ab + (size_t)row * K + k0 + chd * 8, As + c * 8);
      g2l16(Bb + (size_t)row * K + k0 + chd * 8, Bs + c * 8);
    }
    __syncthreads();
#pragma unroll
    for (int ks = 0; ks < 2; ++ks) {
      bf16x8 a[4], b[4];
      int chd = ks * 4 + quad;
#pragma unroll
      for (int i = 0; i < 4; ++i) {
        int row = wm + i * 16 + lm;  // row&7 == r3
        a[i] = *(const bf16x8*)(As + (((row >> 3) * 64 + r3 * 8 + (chd ^ r3)) * 8));
      }
#pragma unroll
      for (int j = 0; j < 4; ++j) {
        int row = wn + j * 16 + lm;
        b[j] = *(const bf16x8*)(Bs + (((row >> 3) * 64 + r3 * 8 + (chd ^ r3)) * 8));
      }
#pragma unroll
      for (int i = 0; i < 4; ++i)
#pragma unroll
        for (int j = 0; j < 4; ++j)
          acc[i][j] = MFMA32(a[i], b[j], acc[i][j]);
    }
    __syncthreads();
  }

#pragma unroll
  for (int i = 0; i < 4; ++i)
#pragma unroll
    for (int j = 0; j < 4; ++j)
#pragma unroll
      for (int r = 0; r < 4; ++r) {
        int row = bm + wm + i * 16 + quad * 4 + r;
        int col = bn + wn + j * 16 + lm;
        float v = acc[i][j][r];
        if (BF16_OUT)
          ((u16*)C)[(size_t)row * N + col] = f2b(v);
        else
          ((float*)C)[(size_t)row * N + col] = v;
      }
}

// ---------------- RoPE + head rearrange v2: coalesced VT via LDS transpose ----
__global__ __launch_bounds__(256) void rope_rearrange_v2(const u16* __restrict__ Y,
                                                         u16* __restrict__ Q,
                                                         u16* __restrict__ Kb,
                                                         u16* __restrict__ VT) {
  const float SC = 0.12751744f;  // (1/sqrt(128)) * log2(e)
  __shared__ u16 T[128][68];     // V tile: [d][s_local], padded stride
  const int st = blockIdx.x;     // s-tile (64 rows)
  const int bh = blockIdx.y;     // b*16 + h
  const int b = bh >> 4, h = bh & 15;
  const int tid = threadIdx.x;
  const int d = tid & 127;
  const int sgrp = tid >> 7;  // 0/1

  // hoisted rope frequency (depends only on d)
  float inv = 0.f;
  const int f0 = d & 31;
  if (d >= 64) inv = __powf(10000.0f, -(float)(2 * f0) * (1.0f / 64.0f));

  const u16* Yc = Y + (size_t)(b * 2048 + st * 64) * 6144;

#pragma unroll 4
  for (int k = 0; k < 32; ++k) {
    const int sl = sgrp * 32 + k;
    const int s = st * 64 + sl;
    const u16* Yr = Yc + (size_t)sl * 6144;

    // V -> LDS tile (global read coalesced along d)
    T[d][sl] = Yr[4096 + h * 128 + d];

    float qv, kv;
    if (d < 64) {
      qv = b2f(Yr[h * 64 + d]);
      kv = b2f(Yr[1024 + h * 64 + d]);
    } else {
      float ang = (float)s * inv;
      float sn = sinf(ang), cs = cosf(ang);
      float qx1 = b2f(Yr[2048 + h * 64 + f0]);
      float qx2 = b2f(Yr[2048 + h * 64 + f0 + 32]);
      float kx1 = b2f(Yr[3072 + h * 64 + f0]);
      float kx2 = b2f(Yr[3072 + h * 64 + f0 + 32]);
      if (d < 96) { qv = qx1 * cs - qx2 * sn; kv = kx1 * cs - kx2 * sn; }
      else        { qv = qx1 * sn + qx2 * cs; kv = kx1 * sn + kx2 * cs; }
    }
    size_t qo = ((size_t)bh * 2048 + s) * 128 + d;
    Q[qo] = f2b(qv * SC);
    Kb[qo] = f2b(kv);
  }
  __syncthreads();

  // VT write: row dd gets 64 consecutive s (128B), as ushort4 (8B/lane, coalesced)
#pragma unroll
  for (int it = 0; it < 8; ++it) {
    const int i = it * 256 + tid;
    const int dd = i >> 4;      // 0..127
    const int ch = i & 15;      // 16 x ushort4 per row
    ushort4 v = *(const ushort4*)(&T[dd][ch * 4]);
    *(ushort4*)(VT + ((size_t)bh * 128 + dd) * 2048 + st * 64 + ch * 4) = v;
  }
}

// ---------------- fused causal attention v7: double-buffered async staging ----
// R3's attn exposed the full K/V stage latency every kt-iteration
// (stage -> syncthreads(vmcnt(0) drain) -> compute). v7 (T14/T3-minimum):
//  - Ks/Vs double-buffered (2x16KB each); stage(kt+1 -> other buf) issued FIRST,
//    hides under the current tile's QK^T+softmax+PV (~1.5k cycles >> L2 latency).
//  - vmcnt(0) drain AFTER compute (only this iter's 8 loads outstanding: ~free).
//  - ONE barrier per iteration (v4 had two). Ps barrier dropped: R4's v6 passed
//    with none -> Ps rows are wave-private (each wave writes+reads only
//    rows wrow..wrow+15).
// LDS 73KB -> still 2 blocks/CU (grid is 2 blocks/CU anyway; no occupancy loss).
__global__ __launch_bounds__(256, 2) void attn_v7(const u16* __restrict__ Q,
                                                  const u16* __restrict__ K,
                                                  const u16* __restrict__ VT,
                                                  u16* __restrict__ O) {
  constexpr int S = 2048;
  constexpr int D = 128;
  __shared__ u16 Ks[2][64 * 128];  // chunk-swizzled
  __shared__ u16 Vs[2][128 * 64];  // VT tile [d][s_local], chunk-swizzled
  __shared__ u16 Ps[64 * 72];      // wave-private rows; padded stride 72
  const int bx = blockIdx.x;
  const int bh = blockIdx.y;
  const int b = bh >> 4, h = bh & 15;
  const int tid = threadIdx.x, wid = tid >> 6, lane = tid & 63;
  const int lm = lane & 15, quad = lane >> 4;
  const int rx = lm & 7;
  const int wrow = wid * 16;

  const u16* Kbh = K + (size_t)bh * S * D;
  const u16* Vbh = VT + (size_t)bh * D * S;

  // issue the 8 async loads staging K/V tile kt into buffer bufid
  auto stageKV = [&](int kt, int bufid) {
    const u16* Kt = Kbh + (size_t)kt * 64 * D;
    const u16* Vt = Vbh + (size_t)kt * 64;
#pragma unroll
    for (int it = 0; it < 4; ++it) {
      int c = it * 256 + tid;
      int row = c >> 4, u = c & 15;
      g2l16(Kt + (size_t)row * 128 + (size_t)(u ^ (row & 7)) * 8, &Ks[bufid][c * 8]);
    }
#pragma unroll
    for (int it = 0; it < 4; ++it) {
      int c = it * 256 + tid;
      int row = c >> 3, u = c & 7;
      g2l16(Vt + (size_t)row * S + (size_t)(u ^ (row & 7)) * 8, &Vs[bufid][c * 8]);
    }
  };

#pragma unroll 1
  for (int pass = 0; pass < 2; ++pass) {
    const int qt = pass == 0 ? bx : 31 - bx;

    // Q A-operand fragments direct from global
    bf16x8 aq[4];
#pragma unroll
    for (int ks = 0; ks < 4; ++ks)
      aq[ks] = *(const bf16x8*)(Q + ((size_t)bh * S + (size_t)qt * 64 + wrow + lm) * D +
                                ks * 32 + quad * 8);

    float l_r[4] = {0.f, 0.f, 0.f, 0.f};
    f32x4 zero = {0.f, 0.f, 0.f, 0.f};
    f32x4 oacc[8];
#pragma unroll
    for (int t = 0; t < 8; ++t) oacc[t] = zero;

    // prologue: stage tile 0 into buf0 (previous pass's end barrier made
    // both buffers safe to overwrite)
    stageKV(0, 0);
    asm volatile("s_waitcnt vmcnt(0)" ::: "memory");
    __builtin_amdgcn_s_barrier();

#pragma unroll 1
    for (int kt = 0; kt <= qt; ++kt) {
      const int cur = kt & 1;
      // issue next tile's stage FIRST: latency hides under this tile's compute
      if (kt < qt) stageKV(kt + 1, cur ^ 1);

      // S-tile = Q K^T from Ks[cur]
      f32x4 sc[4];
#pragma unroll
      for (int j = 0; j < 4; ++j) sc[j] = zero;
      __builtin_amdgcn_s_setprio(1);
#pragma unroll
      for (int ks = 0; ks < 4; ++ks) {
        const int kc = ks * 4 + quad;
#pragma unroll
        for (int j = 0; j < 4; ++j) {
          bf16x8 bk = *(const bf16x8*)(&Ks[cur][((j * 16 + lm) * 16 + (kc ^ rx)) * 8]);
          sc[j] = MFMA32(aq[ks], bk, sc[j]);
        }
      }
      __builtin_amdgcn_s_setprio(0);

      const bool diag = (kt == qt);
#pragma unroll
      for (int r = 0; r < 4; ++r) {
        const int qcol = wrow + quad * 4 + r;  // q row within this 64-tile
        float pv[4];
        float rs = 0.f;
#pragma unroll
        for (int j = 0; j < 4; ++j) {
          float p = __builtin_amdgcn_exp2f(fminf(sc[j][r], 30.0f));
          if (diag && (j * 16 + lm > qcol)) p = 0.f;
          rs += p;
          pv[j] = p;
        }
#pragma unroll
        for (int dd = 1; dd < 16; dd <<= 1) rs += __shfl_xor(rs, dd);
        l_r[r] += rs;
        const int prow = (wrow + quad * 4 + r) * 72;
#pragma unroll
        for (int j = 0; j < 4; ++j) Ps[prow + j * 16 + lm] = f2b(pv[j]);
      }
      // no barrier: Ps rows are wave-private (proven in R4)

      // O += P @ V from Vs[cur]
      __builtin_amdgcn_s_setprio(1);
#pragma unroll
      for (int ks = 0; ks < 2; ++ks) {
        bf16x8 ap = *(const bf16x8*)(Ps + (wrow + lm) * 72 + ks * 32 + quad * 8);
        const int kc = ks * 4 + quad;
#pragma unroll
        for (int t = 0; t < 8; ++t) {
          bf16x8 bv = *(const bf16x8*)(&Vs[cur][((t * 16 + lm) * 8 + (kc ^ rx)) * 8]);
          oacc[t] = MFMA32(ap, bv, oacc[t]);
        }
      }
      __builtin_amdgcn_s_setprio(0);

      // own stage loads done (issued ~1.5k cycles ago -> near-free), then one
      // barrier: all waves done reading cur buffer AND all stage data visible
      if (kt < qt) asm volatile("s_waitcnt vmcnt(0)" ::: "memory");
      __builtin_amdgcn_s_barrier();
    }

    // epilogue: O row = b*S + s, col = h*128 + d  (bf16)
#pragma unroll
    for (int r = 0; r < 4; ++r) {
      float inv = 1.0f / l_r[r];
      const int srow = qt * 64 + wrow + quad * 4 + r;
      u16* Orow = O + ((size_t)b * S + srow) * 2048 + h * 128;
#pragma unroll
      for (int t = 0; t < 8; ++t) Orow[t * 16 + lm] = f2b(oacc[t][r] * inv);
    }
  }
}

extern "C" void kernel_launch(void* const* d_in, const int* in_sizes, int n_in,
                              void* d_out, int out_size, void* d_ws, size_t ws_size,
                              hipStream_t stream) {
  const float* x      = (const float*)d_in[0];
  const float* Wq_sem = (const float*)d_in[1];
  const float* Wk_sem = (const float*)d_in[2];
  const float* Wq_geo = (const float*)d_in[3];
  const float* Wk_geo = (const float*)d_in[4];
  const float* Wv     = (const float*)d_in[5];
  const float* Wo     = (const float*)d_in[6];

  char* ws = (char*)d_ws;
  // layout (bytes):
  //   [0, 16M)          xb  (x bf16, 4096x2048)        -> later reused as Q
  //   [16M, 41.2M)      Wall (6144x2048 bf16)          -> later reused as O
  //   [41.2M, 49.6M)    Wob  (2048x2048 bf16)
  //   [49.6M, 99.9M)    Y    (4096x6144 bf16)
  // d_out (33.5MB) used as scratch for K (16.7M) + VT (16.7M) until final GEMM.
  u16* xb   = (u16*)(ws);
  u16* Wall = (u16*)(ws + 16777216);
  u16* Wob  = (u16*)(ws + 16777216 + 25165824);
  u16* Y    = (u16*)(ws + 16777216 + 25165824 + 8388608);
  u16* Qb   = xb;
  u16* Ob   = Wall;
  u16* Kb   = (u16*)d_out;
  u16* VT   = (u16*)((char*)d_out + 16777216);

  // casts to bf16 (2 launches)
  cast_f2b_v4<<<8192, 256, 0, stream>>>(x, xb, 2097152);
  cast_weights<<<16384, 256, 0, stream>>>(Wq_sem, Wk_sem, Wq_geo, Wk_geo, Wv, Wo, Wall, Wob);

  // fused QKV projection: Y = x @ Wall^T   (M=4096, N=6144, K=2048)
  gemm_bt<true><<<dim3(48, 32), 256, 0, stream>>>(xb, Wall, Y, 6144, 2048);

  // RoPE + head split/rearrange (Q pre-scaled by 1/sqrt(128)*log2e)
  rope_rearrange_v2<<<dim3(32, 32), 256, 0, stream>>>(Y, Qb, Kb, VT);

  // causal flash attention -> O (B*S, 2048) bf16
  attn_v7<<<dim3(16, 32), 256, 0, stream>>>(Qb, Kb, VT, Ob);

  // final projection: out = O @ Wo^T  (M=4096, N=2048, K=2048), fp32 out
  gemm_bt<false><<<dim3(16, 32), 256, 0, stream>>>(Ob, Wob, d_out, 2048, 2048);
}

// Round 6
// 391.774 us; speedup vs baseline: 1.5558x; 1.0598x over previous
//
#include <hip/hip_runtime.h>
#include <cstdint>
#include <cstddef>

typedef unsigned short u16;
typedef __attribute__((ext_vector_type(8))) short bf16x8;
typedef __attribute__((ext_vector_type(4))) float f32x4;

#define MFMA32(a, b, c) __builtin_amdgcn_mfma_f32_16x16x32_bf16(a, b, c, 0, 0, 0)

__device__ __forceinline__ u16 f2b(float f) {
  union { float f; unsigned u; } v; v.f = f;
  unsigned u = v.u;
  return (u16)((u + 0x7fffu + ((u >> 16) & 1u)) >> 16);
}
__device__ __forceinline__ float b2f(u16 h) {
  union { unsigned u; float f; } v; v.u = ((unsigned)h) << 16;
  return v.f;
}

// async global->LDS, 16B per lane. LDS dest must be wave-uniform base + lane*16.
__device__ __forceinline__ void g2l16(const void* g, void* l) {
  __builtin_amdgcn_global_load_lds((__attribute__((address_space(1))) void*)(g),
                                   (__attribute__((address_space(3))) void*)(l), 16, 0, 0);
}

// ---------------- fp32 -> bf16 cast (vectorized x4) ----------------
__global__ __launch_bounds__(256) void cast_f2b_v4(const float* __restrict__ in,
                                                   u16* __restrict__ out, int n4) {
  int i = blockIdx.x * 256 + threadIdx.x;
  if (i >= n4) return;
  float4 v = ((const float4*)in)[i];
  ushort4 r;
  r.x = f2b(v.x); r.y = f2b(v.y); r.z = f2b(v.z); r.w = f2b(v.w);
  ((ushort4*)out)[i] = r;
}

// ---------------- all weight casts in ONE launch (cuts 5 dispatch gaps) -------
__global__ __launch_bounds__(256) void cast_weights(const float* __restrict__ W0,
                                                    const float* __restrict__ W1,
                                                    const float* __restrict__ W2,
                                                    const float* __restrict__ W3,
                                                    const float* __restrict__ Wv,
                                                    const float* __restrict__ Wo,
                                                    u16* __restrict__ Wall,
                                                    u16* __restrict__ Wob) {
  const int blk = blockIdx.x;
  const float* src;
  u16* dst;
  int li;
  if (blk < 8192) {
    const int s = blk >> 11;  // uniform per block
    src = s == 0 ? W0 : s == 1 ? W1 : s == 2 ? W2 : W3;
    dst = Wall + (size_t)s * 2097152;
    li = (blk & 2047) * 256 + threadIdx.x;
  } else if (blk < 12288) {
    src = Wv;
    dst = Wall + (size_t)4 * 2097152;
    li = (blk - 8192) * 256 + threadIdx.x;
  } else {
    src = Wo;
    dst = Wob;
    li = (blk - 12288) * 256 + threadIdx.x;
  }
  float4 v = ((const float4*)src)[li];
  ushort4 r;
  r.x = f2b(v.x); r.y = f2b(v.y); r.z = f2b(v.z); r.w = f2b(v.w);
  ((ushort4*)dst)[li] = r;
}

// ---------------- C = A @ B^T   (A: MxK bf16, B: NxK bf16, both K-major) ------
// 128x128 tile, BK=64, 4 waves (2x2), 4x4 MFMA/wave. XOR-chunk-swizzled LDS.
template <bool BF16_OUT>
__global__ __launch_bounds__(256) void gemm_bt(const u16* __restrict__ A,
                                               const u16* __restrict__ B,
                                               void* __restrict__ C, int N, int K) {
  __shared__ u16 As[128 * 64];
  __shared__ u16 Bs[128 * 64];
  const int tid = threadIdx.x;
  const int wid = tid >> 6;
  const int lane = tid & 63;
  const int lm = lane & 15;
  const int quad = lane >> 4;
  const int r3 = lm & 7;
  const int wm = (wid & 1) * 64;
  const int wn = (wid >> 1) * 64;
  const int bm = blockIdx.y * 128;
  const int bn = blockIdx.x * 128;

  const u16* Ab = A + (size_t)bm * K;
  const u16* Bb = B + (size_t)bn * K;

  f32x4 zero = {0.f, 0.f, 0.f, 0.f};
  f32x4 acc[4][4];
#pragma unroll
  for (int i = 0; i < 4; ++i)
#pragma unroll
    for (int j = 0; j < 4; ++j) acc[i][j] = zero;

  for (int k0 = 0; k0 < K; k0 += 64) {
#pragma unroll
    for (int it = 0; it < 4; ++it) {
      int c = it * 256 + tid;
      int rg = c >> 6, rw = (c >> 3) & 7, u = c & 7;
      int row = rg * 8 + rw;
      int chd = u ^ rw;  // store chunk (row, chd) at linear chunk c
      g2l16(Ab + (size_t)row * K + k0 + chd * 8, As + c * 8);
      g2l16(Bb + (size_t)row * K + k0 + chd * 8, Bs + c * 8);
    }
    __syncthreads();
#pragma unroll
    for (int ks = 0; ks < 2; ++ks) {
      bf16x8 a[4], b[4];
      int chd = ks * 4 + quad;
#pragma unroll
      for (int i = 0; i < 4; ++i) {
        int row = wm + i * 16 + lm;  // row&7 == r3
        a[i] = *(const bf16x8*)(As + (((row >> 3) * 64 + r3 * 8 + (chd ^ r3)) * 8));
      }
#pragma unroll
      for (int j = 0; j < 4; ++j) {
        int row = wn + j * 16 + lm;
        b[j] = *(const bf16x8*)(Bs + (((row >> 3) * 64 + r3 * 8 + (chd ^ r3)) * 8));
      }
#pragma unroll
      for (int i = 0; i < 4; ++i)
#pragma unroll
        for (int j = 0; j < 4; ++j)
          acc[i][j] = MFMA32(a[i], b[j], acc[i][j]);
    }
    __syncthreads();
  }

#pragma unroll
  for (int i = 0; i < 4; ++i)
#pragma unroll
    for (int j = 0; j < 4; ++j)
#pragma unroll
      for (int r = 0; r < 4; ++r) {
        int row = bm + wm + i * 16 + quad * 4 + r;
        int col = bn + wn + j * 16 + lm;
        float v = acc[i][j][r];
        if (BF16_OUT)
          ((u16*)C)[(size_t)row * N + col] = f2b(v);
        else
          ((float*)C)[(size_t)row * N + col] = v;
      }
}

// ---------------- RoPE + head rearrange v2: coalesced VT via LDS transpose ----
__global__ __launch_bounds__(256) void rope_rearrange_v2(const u16* __restrict__ Y,
                                                         u16* __restrict__ Q,
                                                         u16* __restrict__ Kb,
                                                         u16* __restrict__ VT) {
  const float SC = 0.12751744f;  // (1/sqrt(128)) * log2(e)
  __shared__ u16 T[128][68];     // V tile: [d][s_local], padded stride
  const int st = blockIdx.x;     // s-tile (64 rows)
  const int bh = blockIdx.y;     // b*16 + h
  const int b = bh >> 4, h = bh & 15;
  const int tid = threadIdx.x;
  const int d = tid & 127;
  const int sgrp = tid >> 7;  // 0/1

  // hoisted rope frequency (depends only on d)
  float inv = 0.f;
  const int f0 = d & 31;
  if (d >= 64) inv = __powf(10000.0f, -(float)(2 * f0) * (1.0f / 64.0f));

  const u16* Yc = Y + (size_t)(b * 2048 + st * 64) * 6144;

#pragma unroll 4
  for (int k = 0; k < 32; ++k) {
    const int sl = sgrp * 32 + k;
    const int s = st * 64 + sl;
    const u16* Yr = Yc + (size_t)sl * 6144;

    // V -> LDS tile (global read coalesced along d)
    T[d][sl] = Yr[4096 + h * 128 + d];

    float qv, kv;
    if (d < 64) {
      qv = b2f(Yr[h * 64 + d]);
      kv = b2f(Yr[1024 + h * 64 + d]);
    } else {
      float ang = (float)s * inv;
      float sn = sinf(ang), cs = cosf(ang);
      float qx1 = b2f(Yr[2048 + h * 64 + f0]);
      float qx2 = b2f(Yr[2048 + h * 64 + f0 + 32]);
      float kx1 = b2f(Yr[3072 + h * 64 + f0]);
      float kx2 = b2f(Yr[3072 + h * 64 + f0 + 32]);
      if (d < 96) { qv = qx1 * cs - qx2 * sn; kv = kx1 * cs - kx2 * sn; }
      else        { qv = qx1 * sn + qx2 * cs; kv = kx1 * sn + kx2 * cs; }
    }
    size_t qo = ((size_t)bh * 2048 + s) * 128 + d;
    Q[qo] = f2b(qv * SC);
    Kb[qo] = f2b(kv);
  }
  __syncthreads();

  // VT write: row dd gets 64 consecutive s (128B), as ushort4 (8B/lane, coalesced)
#pragma unroll
  for (int it = 0; it < 8; ++it) {
    const int i = it * 256 + tid;
    const int dd = i >> 4;      // 0..127
    const int ch = i & 15;      // 16 x ushort4 per row
    ushort4 v = *(const ushort4*)(&T[dd][ch * 4]);
    *(ushort4*)(VT + ((size_t)bh * 128 + dd) * 2048 + st * 64 + ch * 4) = v;
  }
}

// ---------------- fused causal attention v8: v7 + XCD-affinity block remap ----
// FETCH_SIZE was 253MB ~= 8 x (K+VT total 33.5MB): linear bid = x + 16*y,
// XCD = bid%8 = x%8, so the 16 qt-blocks sharing a bh's 1MB K/VT slice were
// sprayed across all 8 XCD L2s -> each XCD refetched the slice (L3 stream,
// ~2.4 TB/s = the real attn ceiling; staging latency already hidden per R5).
// Remap (bijective, 512 = 8 xcd x 4 bh x 16 qt): XCD x owns bh 4x..4x+3;
// per-XCD working set = 4 x 1MB = its 4MB L2. Work/block is 33 kt-tiles for
// every block (bx & 31-bx pairing) -> balance preserved.
__global__ __launch_bounds__(256, 2) void attn_v8(const u16* __restrict__ Q,
                                                  const u16* __restrict__ K,
                                                  const u16* __restrict__ VT,
                                                  u16* __restrict__ O) {
  constexpr int S = 2048;
  constexpr int D = 128;
  __shared__ u16 Ks[2][64 * 128];  // chunk-swizzled
  __shared__ u16 Vs[2][128 * 64];  // VT tile [d][s_local], chunk-swizzled
  __shared__ u16 Ps[64 * 72];      // wave-private rows; padded stride 72
  const int linear = blockIdx.x + (blockIdx.y << 4);
  const int xcd = linear & 7;
  const int slot = linear >> 3;          // 0..63
  const int bh = (xcd << 2) + (slot >> 4);
  const int bx = slot & 15;
  const int b = bh >> 4, h = bh & 15;
  const int tid = threadIdx.x, wid = tid >> 6, lane = tid & 63;
  const int lm = lane & 15, quad = lane >> 4;
  const int rx = lm & 7;
  const int wrow = wid * 16;

  const u16* Kbh = K + (size_t)bh * S * D;
  const u16* Vbh = VT + (size_t)bh * D * S;

  // issue the 8 async loads staging K/V tile kt into buffer bufid
  auto stageKV = [&](int kt, int bufid) {
    const u16* Kt = Kbh + (size_t)kt * 64 * D;
    const u16* Vt = Vbh + (size_t)kt * 64;
#pragma unroll
    for (int it = 0; it < 4; ++it) {
      int c = it * 256 + tid;
      int row = c >> 4, u = c & 15;
      g2l16(Kt + (size_t)row * 128 + (size_t)(u ^ (row & 7)) * 8, &Ks[bufid][c * 8]);
    }
#pragma unroll
    for (int it = 0; it < 4; ++it) {
      int c = it * 256 + tid;
      int row = c >> 3, u = c & 7;
      g2l16(Vt + (size_t)row * S + (size_t)(u ^ (row & 7)) * 8, &Vs[bufid][c * 8]);
    }
  };

#pragma unroll 1
  for (int pass = 0; pass < 2; ++pass) {
    const int qt = pass == 0 ? bx : 31 - bx;

    // Q A-operand fragments direct from global
    bf16x8 aq[4];
#pragma unroll
    for (int ks = 0; ks < 4; ++ks)
      aq[ks] = *(const bf16x8*)(Q + ((size_t)bh * S + (size_t)qt * 64 + wrow + lm) * D +
                                ks * 32 + quad * 8);

    float l_r[4] = {0.f, 0.f, 0.f, 0.f};
    f32x4 zero = {0.f, 0.f, 0.f, 0.f};
    f32x4 oacc[8];
#pragma unroll
    for (int t = 0; t < 8; ++t) oacc[t] = zero;

    // prologue: stage tile 0 into buf0
    stageKV(0, 0);
    asm volatile("s_waitcnt vmcnt(0)" ::: "memory");
    __builtin_amdgcn_s_barrier();

#pragma unroll 1
    for (int kt = 0; kt <= qt; ++kt) {
      const int cur = kt & 1;
      // issue next tile's stage FIRST: latency hides under this tile's compute
      if (kt < qt) stageKV(kt + 1, cur ^ 1);

      // S-tile = Q K^T from Ks[cur]
      f32x4 sc[4];
#pragma unroll
      for (int j = 0; j < 4; ++j) sc[j] = zero;
      __builtin_amdgcn_s_setprio(1);
#pragma unroll
      for (int ks = 0; ks < 4; ++ks) {
        const int kc = ks * 4 + quad;
#pragma unroll
        for (int j = 0; j < 4; ++j) {
          bf16x8 bk = *(const bf16x8*)(&Ks[cur][((j * 16 + lm) * 16 + (kc ^ rx)) * 8]);
          sc[j] = MFMA32(aq[ks], bk, sc[j]);
        }
      }
      __builtin_amdgcn_s_setprio(0);

      const bool diag = (kt == qt);
#pragma unroll
      for (int r = 0; r < 4; ++r) {
        const int qcol = wrow + quad * 4 + r;  // q row within this 64-tile
        float pv[4];
        float rs = 0.f;
#pragma unroll
        for (int j = 0; j < 4; ++j) {
          float p = __builtin_amdgcn_exp2f(fminf(sc[j][r], 30.0f));
          if (diag && (j * 16 + lm > qcol)) p = 0.f;
          rs += p;
          pv[j] = p;
        }
#pragma unroll
        for (int dd = 1; dd < 16; dd <<= 1) rs += __shfl_xor(rs, dd);
        l_r[r] += rs;
        const int prow = (wrow + quad * 4 + r) * 72;
#pragma unroll
        for (int j = 0; j < 4; ++j) Ps[prow + j * 16 + lm] = f2b(pv[j]);
      }
      // no barrier: Ps rows are wave-private (proven in R4)

      // O += P @ V from Vs[cur]
      __builtin_amdgcn_s_setprio(1);
#pragma unroll
      for (int ks = 0; ks < 2; ++ks) {
        bf16x8 ap = *(const bf16x8*)(Ps + (wrow + lm) * 72 + ks * 32 + quad * 8);
        const int kc = ks * 4 + quad;
#pragma unroll
        for (int t = 0; t < 8; ++t) {
          bf16x8 bv = *(const bf16x8*)(&Vs[cur][((t * 16 + lm) * 8 + (kc ^ rx)) * 8]);
          oacc[t] = MFMA32(ap, bv, oacc[t]);
        }
      }
      __builtin_amdgcn_s_setprio(0);

      // own stage loads done, then one barrier
      if (kt < qt) asm volatile("s_waitcnt vmcnt(0)" ::: "memory");
      __builtin_amdgcn_s_barrier();
    }

    // epilogue: O row = b*S + s, col = h*128 + d  (bf16)
#pragma unroll
    for (int r = 0; r < 4; ++r) {
      float inv = 1.0f / l_r[r];
      const int srow = qt * 64 + wrow + quad * 4 + r;
      u16* Orow = O + ((size_t)b * S + srow) * 2048 + h * 128;
#pragma unroll
      for (int t = 0; t < 8; ++t) Orow[t * 16 + lm] = f2b(oacc[t][r] * inv);
    }
  }
}

extern "C" void kernel_launch(void* const* d_in, const int* in_sizes, int n_in,
                              void* d_out, int out_size, void* d_ws, size_t ws_size,
                              hipStream_t stream) {
  const float* x      = (const float*)d_in[0];
  const float* Wq_sem = (const float*)d_in[1];
  const float* Wk_sem = (const float*)d_in[2];
  const float* Wq_geo = (const float*)d_in[3];
  const float* Wk_geo = (const float*)d_in[4];
  const float* Wv     = (const float*)d_in[5];
  const float* Wo     = (const float*)d_in[6];

  char* ws = (char*)d_ws;
  // layout (bytes):
  //   [0, 16M)          xb  (x bf16, 4096x2048)        -> later reused as Q
  //   [16M, 41.2M)      Wall (6144x2048 bf16)          -> later reused as O
  //   [41.2M, 49.6M)    Wob  (2048x2048 bf16)
  //   [49.6M, 99.9M)    Y    (4096x6144 bf16)
  // d_out (33.5MB) used as scratch for K (16.7M) + VT (16.7M) until final GEMM.
  u16* xb   = (u16*)(ws);
  u16* Wall = (u16*)(ws + 16777216);
  u16* Wob  = (u16*)(ws + 16777216 + 25165824);
  u16* Y    = (u16*)(ws + 16777216 + 25165824 + 8388608);
  u16* Qb   = xb;
  u16* Ob   = Wall;
  u16* Kb   = (u16*)d_out;
  u16* VT   = (u16*)((char*)d_out + 16777216);

  // casts to bf16 (2 launches)
  cast_f2b_v4<<<8192, 256, 0, stream>>>(x, xb, 2097152);
  cast_weights<<<16384, 256, 0, stream>>>(Wq_sem, Wk_sem, Wq_geo, Wk_geo, Wv, Wo, Wall, Wob);

  // fused QKV projection: Y = x @ Wall^T   (M=4096, N=6144, K=2048)
  gemm_bt<true><<<dim3(48, 32), 256, 0, stream>>>(xb, Wall, Y, 6144, 2048);

  // RoPE + head split/rearrange (Q pre-scaled by 1/sqrt(128)*log2e)
  rope_rearrange_v2<<<dim3(32, 32), 256, 0, stream>>>(Y, Qb, Kb, VT);

  // causal flash attention -> O (B*S, 2048) bf16
  attn_v8<<<dim3(16, 32), 256, 0, stream>>>(Qb, Kb, VT, Ob);

  // final projection: out = O @ Wo^T  (M=4096, N=2048, K=2048), fp32 out
  gemm_bt<false><<<dim3(16, 32), 256, 0, stream>>>(Ob, Wob, d_out, 2048, 2048);
}

// Round 7
// 391.703 us; speedup vs baseline: 1.5561x; 1.0002x over previous
//
#include <hip/hip_runtime.h>
#include <cstdint>
#include <cstddef>

typedef unsigned short u16;
typedef __attribute__((ext_vector_type(8))) short bf16x8;
typedef __attribute__((ext_vector_type(4))) float f32x4;

#define MFMA32(a, b, c) __builtin_amdgcn_mfma_f32_16x16x32_bf16(a, b, c, 0, 0, 0)

__device__ __forceinline__ u16 f2b(float f) {
  union { float f; unsigned u; } v; v.f = f;
  unsigned u = v.u;
  return (u16)((u + 0x7fffu + ((u >> 16) & 1u)) >> 16);
}
__device__ __forceinline__ float b2f(u16 h) {
  union { unsigned u; float f; } v; v.u = ((unsigned)h) << 16;
  return v.f;
}

// async global->LDS, 16B per lane. LDS dest must be wave-uniform base + lane*16.
__device__ __forceinline__ void g2l16(const void* g, void* l) {
  __builtin_amdgcn_global_load_lds((__attribute__((address_space(1))) void*)(g),
                                   (__attribute__((address_space(3))) void*)(l), 16, 0, 0);
}

// ---------------- fp32 -> bf16 cast (vectorized x4) ----------------
__global__ __launch_bounds__(256) void cast_f2b_v4(const float* __restrict__ in,
                                                   u16* __restrict__ out, int n4) {
  int i = blockIdx.x * 256 + threadIdx.x;
  if (i >= n4) return;
  float4 v = ((const float4*)in)[i];
  ushort4 r;
  r.x = f2b(v.x); r.y = f2b(v.y); r.z = f2b(v.z); r.w = f2b(v.w);
  ((ushort4*)out)[i] = r;
}

// ---------------- all weight casts in ONE launch ----------------
__global__ __launch_bounds__(256) void cast_weights(const float* __restrict__ W0,
                                                    const float* __restrict__ W1,
                                                    const float* __restrict__ W2,
                                                    const float* __restrict__ W3,
                                                    const float* __restrict__ Wv,
                                                    const float* __restrict__ Wo,
                                                    u16* __restrict__ Wall,
                                                    u16* __restrict__ Wob) {
  const int blk = blockIdx.x;
  const float* src;
  u16* dst;
  int li;
  if (blk < 8192) {
    const int s = blk >> 11;  // uniform per block
    src = s == 0 ? W0 : s == 1 ? W1 : s == 2 ? W2 : W3;
    dst = Wall + (size_t)s * 2097152;
    li = (blk & 2047) * 256 + threadIdx.x;
  } else if (blk < 12288) {
    src = Wv;
    dst = Wall + (size_t)4 * 2097152;
    li = (blk - 8192) * 256 + threadIdx.x;
  } else {
    src = Wo;
    dst = Wob;
    li = (blk - 12288) * 256 + threadIdx.x;
  }
  float4 v = ((const float4*)src)[li];
  ushort4 r;
  r.x = f2b(v.x); r.y = f2b(v.y); r.z = f2b(v.z); r.w = f2b(v.w);
  ((ushort4*)dst)[li] = r;
}

// ---------------- C = A @ B^T  128x128 tile (m97 structure; final projection) -
template <bool BF16_OUT>
__global__ __launch_bounds__(256) void gemm_bt(const u16* __restrict__ A,
                                               const u16* __restrict__ B,
                                               void* __restrict__ C, int N, int K) {
  __shared__ u16 As[128 * 64];
  __shared__ u16 Bs[128 * 64];
  const int tid = threadIdx.x;
  const int wid = tid >> 6;
  const int lane = tid & 63;
  const int lm = lane & 15;
  const int quad = lane >> 4;
  const int r3 = lm & 7;
  const int wm = (wid & 1) * 64;
  const int wn = (wid >> 1) * 64;
  const int bm = blockIdx.y * 128;
  const int bn = blockIdx.x * 128;

  const u16* Ab = A + (size_t)bm * K;
  const u16* Bb = B + (size_t)bn * K;

  f32x4 zero = {0.f, 0.f, 0.f, 0.f};
  f32x4 acc[4][4];
#pragma unroll
  for (int i = 0; i < 4; ++i)
#pragma unroll
    for (int j = 0; j < 4; ++j) acc[i][j] = zero;

  for (int k0 = 0; k0 < K; k0 += 64) {
#pragma unroll
    for (int it = 0; it < 4; ++it) {
      int c = it * 256 + tid;
      int rg = c >> 6, rw = (c >> 3) & 7, u = c & 7;
      int row = rg * 8 + rw;
      int chd = u ^ rw;  // store chunk (row, chd) at linear chunk c
      g2l16(Ab + (size_t)row * K + k0 + chd * 8, As + c * 8);
      g2l16(Bb + (size_t)row * K + k0 + chd * 8, Bs + c * 8);
    }
    __syncthreads();
#pragma unroll
    for (int ks = 0; ks < 2; ++ks) {
      bf16x8 a[4], b[4];
      int chd = ks * 4 + quad;
#pragma unroll
      for (int i = 0; i < 4; ++i) {
        int row = wm + i * 16 + lm;  // row&7 == r3
        a[i] = *(const bf16x8*)(As + (((row >> 3) * 64 + r3 * 8 + (chd ^ r3)) * 8));
      }
#pragma unroll
      for (int j = 0; j < 4; ++j) {
        int row = wn + j * 16 + lm;
        b[j] = *(const bf16x8*)(Bs + (((row >> 3) * 64 + r3 * 8 + (chd ^ r3)) * 8));
      }
#pragma unroll
      for (int i = 0; i < 4; ++i)
#pragma unroll
        for (int j = 0; j < 4; ++j)
          acc[i][j] = MFMA32(a[i], b[j], acc[i][j]);
    }
    __syncthreads();
  }

#pragma unroll
  for (int i = 0; i < 4; ++i)
#pragma unroll
    for (int j = 0; j < 4; ++j)
#pragma unroll
      for (int r = 0; r < 4; ++r) {
        int row = bm + wm + i * 16 + quad * 4 + r;
        int col = bn + wn + j * 16 + lm;
        float v = acc[i][j][r];
        if (BF16_OUT)
          ((u16*)C)[(size_t)row * N + col] = f2b(v);
        else
          ((float*)C)[(size_t)row * N + col] = v;
      }
}

// ---------------- C = A @ B^T  256x256, 8-phase counted-vmcnt (T2+T3+T4+T5) ---
// Fixes R2's failed port: (1) per-phase SUBTILE ds_reads (12/4/8/0 pattern,
// quad order (0,0)(0,1)(1,1)(1,0) so bB(nh0) is held in regs for ph3) instead
// of bunching 24 reads at ph0/ph4; (2) frag regs sized to fit 2 waves/SIMD
// (aA[4][2]+bB[2][2][2]=64 VGPR + 128 acc ~= 220 < 256; R2 spilled).
// Stage queue q=8i+j+5 (1 half-tile = 2 loads/thread per phase):
//   buf0 reads end ph2 (barrier-sealed) -> tile 2i+2 staged ph3..6 into buf0;
//   buf1 reads end ph6 -> tile 2i+3 staged ph7..ph2' into buf1.
// Gates (only ph3/ph7): vmcnt(2) = only the phase's own stage may be in
// flight; everything older (the tile needed next phase) is complete.
// Tail: when the phase's stage is skipped (q>=NH), gate becomes vmcnt(0).
__global__ __launch_bounds__(512, 2) void gemm_bt8(const u16* __restrict__ A,
                                                   const u16* __restrict__ B,
                                                   u16* __restrict__ C, int N, int K) {
  extern __shared__ char smem[];
  u16* sA = (u16*)smem;            // halves: (buf*2+h)*8192 u16 (16KB each)
  u16* sB = (u16*)(smem + 65536);
  const int tid = threadIdx.x;
  const int wid = tid >> 6, lane = tid & 63;
  const int lm = lane & 15, quad = lane >> 4, rx = lm & 7;
  const int wm = wid >> 2;  // M half (128 rows)
  const int wn = wid & 3;   // N quarter (64 cols)
  const int bm = blockIdx.y * 256, bn = blockIdx.x * 256;
  const u16* Ablk = A + (size_t)bm * K;
  const u16* Bblk = B + (size_t)bn * K;

  f32x4 zero = {0.f, 0.f, 0.f, 0.f};
  f32x4 acc[8][4];
#pragma unroll
  for (int i = 0; i < 8; ++i)
#pragma unroll
    for (int j = 0; j < 4; ++j) acc[i][j] = zero;

  bf16x8 aA[4][2];      // current mh-group fragments
  bf16x8 bB[2][2][2];   // [nh][jj][ks] — both nh-groups held

  const int NT = K >> 6;
  const int NH = NT << 2;
  const int NIT = NT >> 1;

  auto stageh = [&](int q) {
    const int st = q >> 2, sh = q & 3;
    const int k0 = st << 6;
    const int bf = st & 1;
    const u16* src;
    u16* dst;
    int rowbase;
    if (sh < 2) { src = Ablk; rowbase = sh << 7; dst = sA + (bf * 2 + sh) * 8192; }
    else        { src = Bblk; rowbase = (sh - 2) << 7; dst = sB + (bf * 2 + (sh - 2)) * 8192; }
#pragma unroll
    for (int it = 0; it < 2; ++it) {
      const int c = it * 512 + tid;
      const int r = c >> 3, u = c & 7;
      g2l16(src + (size_t)(rowbase + r) * K + k0 + ((u ^ (r & 7)) << 3), dst + (size_t)c * 8);
    }
  };
  auto ldA = [&](int bf, int mh) {
    const u16* Ah = sA + (bf * 2 + wm) * 8192;
#pragma unroll
    for (int ii = 0; ii < 4; ++ii)
#pragma unroll
      for (int ks = 0; ks < 2; ++ks)
        aA[ii][ks] = *(const bf16x8*)(Ah + ((((mh * 4 + ii) * 16 + lm) * 8 +
                                             ((ks * 4 + quad) ^ rx)) << 3));
  };
  auto ldB = [&](int bf, int nh) {
    const u16* Bh = sB + (bf * 2 + (wn >> 1)) * 8192;
#pragma unroll
    for (int jj = 0; jj < 2; ++jj)
#pragma unroll
      for (int ks = 0; ks < 2; ++ks)
        bB[nh][jj][ks] = *(const bf16x8*)(Bh + ((((wn & 1) * 64 + (nh * 2 + jj) * 16 + lm) * 8 +
                                                 ((ks * 4 + quad) ^ rx)) << 3));
  };
  auto mm = [&](int mh, int nh) {
    __builtin_amdgcn_s_setprio(1);
#pragma unroll
    for (int ii = 0; ii < 4; ++ii)
#pragma unroll
      for (int jj = 0; jj < 2; ++jj)
#pragma unroll
        for (int ks = 0; ks < 2; ++ks)
          acc[mh * 4 + ii][nh * 2 + jj] =
              MFMA32(aA[ii][ks], bB[nh][jj][ks], acc[mh * 4 + ii][nh * 2 + jj]);
    __builtin_amdgcn_s_setprio(0);
  };

  // prologue: stage q=0..4 (tile0 full + tile1 h0)
#pragma unroll
  for (int q = 0; q < 5; ++q) stageh(q);
  asm volatile("s_waitcnt vmcnt(2)" ::: "memory");  // tile0 done; q4 in flight
  __builtin_amdgcn_s_barrier();

#pragma unroll 1
  for (int i = 0; i < NIT; ++i) {
    const int qb = 8 * i;
    // ph0: reads buf0 {aA mh0, bB nh0}; stage t(2i+1)h1 -> buf1
    ldA(0, 0); ldB(0, 0);
    if (qb + 5 < NH) stageh(qb + 5);
    __builtin_amdgcn_s_barrier();
    mm(0, 0);
    __builtin_amdgcn_s_barrier();
    // ph1: reads bB nh1; stage t(2i+1)h2
    ldB(0, 1);
    if (qb + 6 < NH) stageh(qb + 6);
    __builtin_amdgcn_s_barrier();
    mm(0, 1);
    __builtin_amdgcn_s_barrier();
    // ph2: reads aA mh1 (buf0 reads END here); stage t(2i+1)h3
    ldA(0, 1);
    if (qb + 7 < NH) stageh(qb + 7);
    __builtin_amdgcn_s_barrier();
    mm(1, 1);
    __builtin_amdgcn_s_barrier();
    // ph3: no reads; stage t(2i+2)h0 -> buf0 (legal: buf0 sealed at ph2-end);
    // gate: tile 2i+1 complete (only ph3's stage may remain in flight)
    {
      const bool st = (qb + 8 < NH);
      if (st) stageh(qb + 8);
      __builtin_amdgcn_s_barrier();
      mm(1, 0);
      if (st) asm volatile("s_waitcnt vmcnt(2)" ::: "memory");
      else    asm volatile("s_waitcnt vmcnt(0)" ::: "memory");
      __builtin_amdgcn_s_barrier();
    }
    // ph4: reads buf1 {aA mh0, bB nh0}; stage t(2i+2)h1
    ldA(1, 0); ldB(1, 0);
    if (qb + 9 < NH) stageh(qb + 9);
    __builtin_amdgcn_s_barrier();
    mm(0, 0);
    __builtin_amdgcn_s_barrier();
    // ph5
    ldB(1, 1);
    if (qb + 10 < NH) stageh(qb + 10);
    __builtin_amdgcn_s_barrier();
    mm(0, 1);
    __builtin_amdgcn_s_barrier();
    // ph6 (buf1 reads END here)
    ldA(1, 1);
    if (qb + 11 < NH) stageh(qb + 11);
    __builtin_amdgcn_s_barrier();
    mm(1, 1);
    __builtin_amdgcn_s_barrier();
    // ph7: stage t(2i+3)h0 -> buf1 (sealed at ph6-end); gate: tile 2i+2 done
    {
      const bool st = (qb + 12 < NH);
      if (st) stageh(qb + 12);
      __builtin_amdgcn_s_barrier();
      mm(1, 0);
      if (st) asm volatile("s_waitcnt vmcnt(2)" ::: "memory");
      else    asm volatile("s_waitcnt vmcnt(0)" ::: "memory");
      __builtin_amdgcn_s_barrier();
    }
  }

  // epilogue (same verified mapping as R2)
#pragma unroll
  for (int ii = 0; ii < 8; ++ii)
#pragma unroll
    for (int jj = 0; jj < 4; ++jj)
#pragma unroll
      for (int r = 0; r < 4; ++r) {
        const int row = bm + wm * 128 + ii * 16 + quad * 4 + r;
        const int col = bn + wn * 64 + jj * 16 + lm;
        C[(size_t)row * N + col] = f2b(acc[ii][jj][r]);
      }
}

// ---------------- RoPE + head rearrange v2: coalesced VT via LDS transpose ----
__global__ __launch_bounds__(256) void rope_rearrange_v2(const u16* __restrict__ Y,
                                                         u16* __restrict__ Q,
                                                         u16* __restrict__ Kb,
                                                         u16* __restrict__ VT) {
  const float SC = 0.12751744f;  // (1/sqrt(128)) * log2(e)
  __shared__ u16 T[128][68];     // V tile: [d][s_local], padded stride
  const int st = blockIdx.x;     // s-tile (64 rows)
  const int bh = blockIdx.y;     // b*16 + h
  const int b = bh >> 4, h = bh & 15;
  const int tid = threadIdx.x;
  const int d = tid & 127;
  const int sgrp = tid >> 7;  // 0/1

  // hoisted rope frequency (depends only on d)
  float inv = 0.f;
  const int f0 = d & 31;
  if (d >= 64) inv = __powf(10000.0f, -(float)(2 * f0) * (1.0f / 64.0f));

  const u16* Yc = Y + (size_t)(b * 2048 + st * 64) * 6144;

#pragma unroll 4
  for (int k = 0; k < 32; ++k) {
    const int sl = sgrp * 32 + k;
    const int s = st * 64 + sl;
    const u16* Yr = Yc + (size_t)sl * 6144;

    // V -> LDS tile (global read coalesced along d)
    T[d][sl] = Yr[4096 + h * 128 + d];

    float qv, kv;
    if (d < 64) {
      qv = b2f(Yr[h * 64 + d]);
      kv = b2f(Yr[1024 + h * 64 + d]);
    } else {
      float ang = (float)s * inv;
      float sn = sinf(ang), cs = cosf(ang);
      float qx1 = b2f(Yr[2048 + h * 64 + f0]);
      float qx2 = b2f(Yr[2048 + h * 64 + f0 + 32]);
      float kx1 = b2f(Yr[3072 + h * 64 + f0]);
      float kx2 = b2f(Yr[3072 + h * 64 + f0 + 32]);
      if (d < 96) { qv = qx1 * cs - qx2 * sn; kv = kx1 * cs - kx2 * sn; }
      else        { qv = qx1 * sn + qx2 * cs; kv = kx1 * sn + kx2 * cs; }
    }
    size_t qo = ((size_t)bh * 2048 + s) * 128 + d;
    Q[qo] = f2b(qv * SC);
    Kb[qo] = f2b(kv);
  }
  __syncthreads();

  // VT write: row dd gets 64 consecutive s (128B), as ushort4 (8B/lane, coalesced)
#pragma unroll
  for (int it = 0; it < 8; ++it) {
    const int i = it * 256 + tid;
    const int dd = i >> 4;      // 0..127
    const int ch = i & 15;      // 16 x ushort4 per row
    ushort4 v = *(const ushort4*)(&T[dd][ch * 4]);
    *(ushort4*)(VT + ((size_t)bh * 128 + dd) * 2048 + st * 64 + ch * 4) = v;
  }
}

// ---------------- fused causal attention v8 (R6-passed: XCD-affinity remap) ---
__global__ __launch_bounds__(256, 2) void attn_v8(const u16* __restrict__ Q,
                                                  const u16* __restrict__ K,
                                                  const u16* __restrict__ VT,
                                                  u16* __restrict__ O) {
  constexpr int S = 2048;
  constexpr int D = 128;
  __shared__ u16 Ks[2][64 * 128];  // chunk-swizzled
  __shared__ u16 Vs[2][128 * 64];  // VT tile [d][s_local], chunk-swizzled
  __shared__ u16 Ps[64 * 72];      // wave-private rows; padded stride 72
  const int linear = blockIdx.x + (blockIdx.y << 4);
  const int xcd = linear & 7;
  const int slot = linear >> 3;          // 0..63
  const int bh = (xcd << 2) + (slot >> 4);
  const int bx = slot & 15;
  const int b = bh >> 4, h = bh & 15;
  const int tid = threadIdx.x, wid = tid >> 6, lane = tid & 63;
  const int lm = lane & 15, quad = lane >> 4;
  const int rx = lm & 7;
  const int wrow = wid * 16;

  const u16* Kbh = K + (size_t)bh * S * D;
  const u16* Vbh = VT + (size_t)bh * D * S;

  auto stageKV = [&](int kt, int bufid) {
    const u16* Kt = Kbh + (size_t)kt * 64 * D;
    const u16* Vt = Vbh + (size_t)kt * 64;
#pragma unroll
    for (int it = 0; it < 4; ++it) {
      int c = it * 256 + tid;
      int row = c >> 4, u = c & 15;
      g2l16(Kt + (size_t)row * 128 + (size_t)(u ^ (row & 7)) * 8, &Ks[bufid][c * 8]);
    }
#pragma unroll
    for (int it = 0; it < 4; ++it) {
      int c = it * 256 + tid;
      int row = c >> 3, u = c & 7;
      g2l16(Vt + (size_t)row * S + (size_t)(u ^ (row & 7)) * 8, &Vs[bufid][c * 8]);
    }
  };

#pragma unroll 1
  for (int pass = 0; pass < 2; ++pass) {
    const int qt = pass == 0 ? bx : 31 - bx;

    bf16x8 aq[4];
#pragma unroll
    for (int ks = 0; ks < 4; ++ks)
      aq[ks] = *(const bf16x8*)(Q + ((size_t)bh * S + (size_t)qt * 64 + wrow + lm) * D +
                                ks * 32 + quad * 8);

    float l_r[4] = {0.f, 0.f, 0.f, 0.f};
    f32x4 zero = {0.f, 0.f, 0.f, 0.f};
    f32x4 oacc[8];
#pragma unroll
    for (int t = 0; t < 8; ++t) oacc[t] = zero;

    stageKV(0, 0);
    asm volatile("s_waitcnt vmcnt(0)" ::: "memory");
    __builtin_amdgcn_s_barrier();

#pragma unroll 1
    for (int kt = 0; kt <= qt; ++kt) {
      const int cur = kt & 1;
      if (kt < qt) stageKV(kt + 1, cur ^ 1);

      f32x4 sc[4];
#pragma unroll
      for (int j = 0; j < 4; ++j) sc[j] = zero;
      __builtin_amdgcn_s_setprio(1);
#pragma unroll
      for (int ks = 0; ks < 4; ++ks) {
        const int kc = ks * 4 + quad;
#pragma unroll
        for (int j = 0; j < 4; ++j) {
          bf16x8 bk = *(const bf16x8*)(&Ks[cur][((j * 16 + lm) * 16 + (kc ^ rx)) * 8]);
          sc[j] = MFMA32(aq[ks], bk, sc[j]);
        }
      }
      __builtin_amdgcn_s_setprio(0);

      const bool diag = (kt == qt);
#pragma unroll
      for (int r = 0; r < 4; ++r) {
        const int qcol = wrow + quad * 4 + r;
        float pv[4];
        float rs = 0.f;
#pragma unroll
        for (int j = 0; j < 4; ++j) {
          float p = __builtin_amdgcn_exp2f(fminf(sc[j][r], 30.0f));
          if (diag && (j * 16 + lm > qcol)) p = 0.f;
          rs += p;
          pv[j] = p;
        }
#pragma unroll
        for (int dd = 1; dd < 16; dd <<= 1) rs += __shfl_xor(rs, dd);
        l_r[r] += rs;
        const int prow = (wrow + quad * 4 + r) * 72;
#pragma unroll
        for (int j = 0; j < 4; ++j) Ps[prow + j * 16 + lm] = f2b(pv[j]);
      }

      __builtin_amdgcn_s_setprio(1);
#pragma unroll
      for (int ks = 0; ks < 2; ++ks) {
        bf16x8 ap = *(const bf16x8*)(Ps + (wrow + lm) * 72 + ks * 32 + quad * 8);
        const int kc = ks * 4 + quad;
#pragma unroll
        for (int t = 0; t < 8; ++t) {
          bf16x8 bv = *(const bf16x8*)(&Vs[cur][((t * 16 + lm) * 8 + (kc ^ rx)) * 8]);
          oacc[t] = MFMA32(ap, bv, oacc[t]);
        }
      }
      __builtin_amdgcn_s_setprio(0);

      if (kt < qt) asm volatile("s_waitcnt vmcnt(0)" ::: "memory");
      __builtin_amdgcn_s_barrier();
    }

#pragma unroll
    for (int r = 0; r < 4; ++r) {
      float inv = 1.0f / l_r[r];
      const int srow = qt * 64 + wrow + quad * 4 + r;
      u16* Orow = O + ((size_t)b * S + srow) * 2048 + h * 128;
#pragma unroll
      for (int t = 0; t < 8; ++t) Orow[t * 16 + lm] = f2b(oacc[t][r] * inv);
    }
  }
}

extern "C" void kernel_launch(void* const* d_in, const int* in_sizes, int n_in,
                              void* d_out, int out_size, void* d_ws, size_t ws_size,
                              hipStream_t stream) {
  const float* x      = (const float*)d_in[0];
  const float* Wq_sem = (const float*)d_in[1];
  const float* Wk_sem = (const float*)d_in[2];
  const float* Wq_geo = (const float*)d_in[3];
  const float* Wk_geo = (const float*)d_in[4];
  const float* Wv     = (const float*)d_in[5];
  const float* Wo     = (const float*)d_in[6];

  char* ws = (char*)d_ws;
  u16* xb   = (u16*)(ws);
  u16* Wall = (u16*)(ws + 16777216);
  u16* Wob  = (u16*)(ws + 16777216 + 25165824);
  u16* Y    = (u16*)(ws + 16777216 + 25165824 + 8388608);
  u16* Qb   = xb;
  u16* Ob   = Wall;
  u16* Kb   = (u16*)d_out;
  u16* VT   = (u16*)((char*)d_out + 16777216);

  hipFuncSetAttribute((const void*)gemm_bt8,
                      hipFuncAttributeMaxDynamicSharedMemorySize, 131072);

  // casts to bf16 (2 launches)
  cast_f2b_v4<<<8192, 256, 0, stream>>>(x, xb, 2097152);
  cast_weights<<<16384, 256, 0, stream>>>(Wq_sem, Wk_sem, Wq_geo, Wk_geo, Wv, Wo, Wall, Wob);

  // fused QKV projection: Y = x @ Wall^T (M=4096, N=6144, K=2048), 8-phase 256²
  gemm_bt8<<<dim3(24, 16), 512, 131072, stream>>>(xb, Wall, Y, 6144, 2048);

  // RoPE + head split/rearrange (Q pre-scaled by 1/sqrt(128)*log2e)
  rope_rearrange_v2<<<dim3(32, 32), 256, 0, stream>>>(Y, Qb, Kb, VT);

  // causal flash attention -> O (B*S, 2048) bf16
  attn_v8<<<dim3(16, 32), 256, 0, stream>>>(Qb, Kb, VT, Ob);

  // final projection: out = O @ Wo^T  (M=4096, N=2048, K=2048), fp32 out
  gemm_bt<false><<<dim3(16, 32), 256, 0, stream>>>(Ob, Wob, d_out, 2048, 2048);
}

// Round 8
// 373.231 us; speedup vs baseline: 1.6331x; 1.0495x over previous
//
#include <hip/hip_runtime.h>
#include <cstdint>
#include <cstddef>

typedef unsigned short u16;
typedef __attribute__((ext_vector_type(8))) short bf16x8;
typedef __attribute__((ext_vector_type(4))) float f32x4;

#define MFMA32(a, b, c) __builtin_amdgcn_mfma_f32_16x16x32_bf16(a, b, c, 0, 0, 0)

__device__ __forceinline__ u16 f2b(float f) {
  union { float f; unsigned u; } v; v.f = f;
  unsigned u = v.u;
  return (u16)((u + 0x7fffu + ((u >> 16) & 1u)) >> 16);
}
__device__ __forceinline__ float b2f(u16 h) {
  union { unsigned u; float f; } v; v.u = ((unsigned)h) << 16;
  return v.f;
}

// async global->LDS, 16B per lane. LDS dest must be wave-uniform base + lane*16.
__device__ __forceinline__ void g2l16(const void* g, void* l) {
  __builtin_amdgcn_global_load_lds((__attribute__((address_space(1))) void*)(g),
                                   (__attribute__((address_space(3))) void*)(l), 16, 0, 0);
}

// ---------------- fp32 -> bf16 cast (vectorized x4) ----------------
__global__ __launch_bounds__(256) void cast_f2b_v4(const float* __restrict__ in,
                                                   u16* __restrict__ out, int n4) {
  int i = blockIdx.x * 256 + threadIdx.x;
  if (i >= n4) return;
  float4 v = ((const float4*)in)[i];
  ushort4 r;
  r.x = f2b(v.x); r.y = f2b(v.y); r.z = f2b(v.z); r.w = f2b(v.w);
  ((ushort4*)out)[i] = r;
}

// ---------------- all weight casts in ONE launch ----------------
__global__ __launch_bounds__(256) void cast_weights(const float* __restrict__ W0,
                                                    const float* __restrict__ W1,
                                                    const float* __restrict__ W2,
                                                    const float* __restrict__ W3,
                                                    const float* __restrict__ Wv,
                                                    const float* __restrict__ Wo,
                                                    u16* __restrict__ Wall,
                                                    u16* __restrict__ Wob) {
  const int blk = blockIdx.x;
  const float* src;
  u16* dst;
  int li;
  if (blk < 8192) {
    const int s = blk >> 11;  // uniform per block
    src = s == 0 ? W0 : s == 1 ? W1 : s == 2 ? W2 : W3;
    dst = Wall + (size_t)s * 2097152;
    li = (blk & 2047) * 256 + threadIdx.x;
  } else if (blk < 12288) {
    src = Wv;
    dst = Wall + (size_t)4 * 2097152;
    li = (blk - 8192) * 256 + threadIdx.x;
  } else {
    src = Wo;
    dst = Wob;
    li = (blk - 12288) * 256 + threadIdx.x;
  }
  float4 v = ((const float4*)src)[li];
  ushort4 r;
  r.x = f2b(v.x); r.y = f2b(v.y); r.z = f2b(v.z); r.w = f2b(v.w);
  ((ushort4*)dst)[li] = r;
}

// ---------------- C = A @ B^T  128x128 tile (m97 structure; final projection) -
template <bool BF16_OUT>
__global__ __launch_bounds__(256) void gemm_bt(const u16* __restrict__ A,
                                               const u16* __restrict__ B,
                                               void* __restrict__ C, int N, int K) {
  __shared__ u16 As[128 * 64];
  __shared__ u16 Bs[128 * 64];
  const int tid = threadIdx.x;
  const int wid = tid >> 6;
  const int lane = tid & 63;
  const int lm = lane & 15;
  const int quad = lane >> 4;
  const int r3 = lm & 7;
  const int wm = (wid & 1) * 64;
  const int wn = (wid >> 1) * 64;
  const int bm = blockIdx.y * 128;
  const int bn = blockIdx.x * 128;

  const u16* Ab = A + (size_t)bm * K;
  const u16* Bb = B + (size_t)bn * K;

  f32x4 zero = {0.f, 0.f, 0.f, 0.f};
  f32x4 acc[4][4];
#pragma unroll
  for (int i = 0; i < 4; ++i)
#pragma unroll
    for (int j = 0; j < 4; ++j) acc[i][j] = zero;

  for (int k0 = 0; k0 < K; k0 += 64) {
#pragma unroll
    for (int it = 0; it < 4; ++it) {
      int c = it * 256 + tid;
      int rg = c >> 6, rw = (c >> 3) & 7, u = c & 7;
      int row = rg * 8 + rw;
      int chd = u ^ rw;
      g2l16(Ab + (size_t)row * K + k0 + chd * 8, As + c * 8);
      g2l16(Bb + (size_t)row * K + k0 + chd * 8, Bs + c * 8);
    }
    __syncthreads();
#pragma unroll
    for (int ks = 0; ks < 2; ++ks) {
      bf16x8 a[4], b[4];
      int chd = ks * 4 + quad;
#pragma unroll
      for (int i = 0; i < 4; ++i) {
        int row = wm + i * 16 + lm;
        a[i] = *(const bf16x8*)(As + (((row >> 3) * 64 + r3 * 8 + (chd ^ r3)) * 8));
      }
#pragma unroll
      for (int j = 0; j < 4; ++j) {
        int row = wn + j * 16 + lm;
        b[j] = *(const bf16x8*)(Bs + (((row >> 3) * 64 + r3 * 8 + (chd ^ r3)) * 8));
      }
#pragma unroll
      for (int i = 0; i < 4; ++i)
#pragma unroll
        for (int j = 0; j < 4; ++j)
          acc[i][j] = MFMA32(a[i], b[j], acc[i][j]);
    }
    __syncthreads();
  }

#pragma unroll
  for (int i = 0; i < 4; ++i)
#pragma unroll
    for (int j = 0; j < 4; ++j)
#pragma unroll
      for (int r = 0; r < 4; ++r) {
        int row = bm + wm + i * 16 + quad * 4 + r;
        int col = bn + wn + j * 16 + lm;
        float v = acc[i][j][r];
        if (BF16_OUT)
          ((u16*)C)[(size_t)row * N + col] = f2b(v);
        else
          ((float*)C)[(size_t)row * N + col] = v;
      }
}

// ---------------- QKV GEMM with fused RoPE/rearrange epilogue ----------------
// Same verified 128x128 main loop as gemm_bt; instead of writing Y, each block
// writes its tile directly to Q/K/VT. BN=128 tiles never straddle the 1024-col
// segments -> per-block uniform branch. seg = bn>>10: 0 q_sem, 1 k_sem,
// 2 q_geo, 3 k_geo, 4/5 V.
//  - sem: Q/K[(bh*2048+s)*128 + (col&63)]; Q scaled by SC.
//  - geo: RoPE pairs (f0, f0+32) are acc[i][j] / acc[i][j+2] of the SAME thread
//    (col = wn + j*16 + lm; hcol = j*16+lm). f0 = (j&1)*16+lm -> two inv-freqs
//    per thread; rope on the f32 accumulator (more accurate than old bf16-Y path).
//  - V: one head per tile (128 cols). Transposed via LDS (As/Bs reused as
//    [128][66] buffer, two wn-halves), then coalesced ushort4 VT row writes.
__global__ __launch_bounds__(256) void gemm_qkv(const u16* __restrict__ A,
                                                const u16* __restrict__ B,
                                                u16* __restrict__ Qb,
                                                u16* __restrict__ Kb,
                                                u16* __restrict__ VT) {
  constexpr int K = 2048;
  const float SC = 0.12751744f;  // (1/sqrt(128)) * log2(e)
  __shared__ u16 sh[16384];      // As | Bs, reused for V transpose
  u16* As = sh;
  u16* Bs = sh + 8192;
  const int tid = threadIdx.x;
  const int wid = tid >> 6;
  const int lane = tid & 63;
  const int lm = lane & 15;
  const int quad = lane >> 4;
  const int r3 = lm & 7;
  const int wm = (wid & 1) * 64;
  const int wn = (wid >> 1) * 64;
  const int bm = blockIdx.y * 128;
  const int bn = blockIdx.x * 128;

  const u16* Ab = A + (size_t)bm * K;
  const u16* Bb = B + (size_t)bn * K;

  f32x4 zero = {0.f, 0.f, 0.f, 0.f};
  f32x4 acc[4][4];
#pragma unroll
  for (int i = 0; i < 4; ++i)
#pragma unroll
    for (int j = 0; j < 4; ++j) acc[i][j] = zero;

  for (int k0 = 0; k0 < K; k0 += 64) {
#pragma unroll
    for (int it = 0; it < 4; ++it) {
      int c = it * 256 + tid;
      int rg = c >> 6, rw = (c >> 3) & 7, u = c & 7;
      int row = rg * 8 + rw;
      int chd = u ^ rw;
      g2l16(Ab + (size_t)row * K + k0 + chd * 8, As + c * 8);
      g2l16(Bb + (size_t)row * K + k0 + chd * 8, Bs + c * 8);
    }
    __syncthreads();
#pragma unroll
    for (int ks = 0; ks < 2; ++ks) {
      bf16x8 a[4], b[4];
      int chd = ks * 4 + quad;
#pragma unroll
      for (int i = 0; i < 4; ++i) {
        int row = wm + i * 16 + lm;
        a[i] = *(const bf16x8*)(As + (((row >> 3) * 64 + r3 * 8 + (chd ^ r3)) * 8));
      }
#pragma unroll
      for (int j = 0; j < 4; ++j) {
        int row = wn + j * 16 + lm;
        b[j] = *(const bf16x8*)(Bs + (((row >> 3) * 64 + r3 * 8 + (chd ^ r3)) * 8));
      }
#pragma unroll
      for (int i = 0; i < 4; ++i)
#pragma unroll
        for (int j = 0; j < 4; ++j)
          acc[i][j] = MFMA32(a[i], b[j], acc[i][j]);
    }
    __syncthreads();
  }

  const int seg = bn >> 10;       // uniform per block
  const int b = bm >> 11;
  const int sbase = bm & 2047;
  const int h = ((bn + wn) >> 6) & 15;  // head for Q/K segments (j*16+lm < 64)
  const size_t bhQ = (size_t)b * 16 + h;

  if (seg < 2) {
    // ---- sem: direct copy ----
    u16* dst = (seg == 0) ? Qb : Kb;
    const float sc = (seg == 0) ? SC : 1.0f;
#pragma unroll
    for (int i = 0; i < 4; ++i)
#pragma unroll
      for (int r = 0; r < 4; ++r) {
        const int s = sbase + wm + i * 16 + quad * 4 + r;
        u16* base = dst + (bhQ * 2048 + s) * 128;
#pragma unroll
        for (int j = 0; j < 4; ++j) {
          const int d = (wn + j * 16 + lm) & 63;
          base[d] = f2b(acc[i][j][r] * sc);
        }
      }
  } else if (seg < 4) {
    // ---- geo: RoPE in-register, write d in [64,128) ----
    u16* dst = (seg == 2) ? Qb : Kb;
    const float sc = (seg == 2) ? SC : 1.0f;
    const float inv0 = __powf(10000.0f, -(float)(2 * lm) * (1.0f / 64.0f));
    const float inv1 = __powf(10000.0f, -(float)(2 * (16 + lm)) * (1.0f / 64.0f));
#pragma unroll
    for (int i = 0; i < 4; ++i)
#pragma unroll
      for (int r = 0; r < 4; ++r) {
        const int s = sbase + wm + i * 16 + quad * 4 + r;
        float sn0, cs0, sn1, cs1;
        __sincosf((float)s * inv0, &sn0, &cs0);
        __sincosf((float)s * inv1, &sn1, &cs1);
        const float x1a = acc[i][0][r], x2a = acc[i][2][r];  // f0 = lm
        const float x1b = acc[i][1][r], x2b = acc[i][3][r];  // f0 = 16+lm
        u16* base = dst + (bhQ * 2048 + s) * 128 + 64;
        base[lm]      = f2b((x1a * cs0 - x2a * sn0) * sc);  // dg = lm
        base[16 + lm] = f2b((x1b * cs1 - x2b * sn1) * sc);  // dg = 16+lm
        base[32 + lm] = f2b((x1a * sn0 + x2a * cs0) * sc);  // dg = 32+lm
        base[48 + lm] = f2b((x1b * sn1 + x2b * cs1) * sc);  // dg = 48+lm
      }
  } else {
    // ---- V: transpose via LDS (reuse sh), coalesced VT row writes ----
    const int hv = (bn - 4096) >> 7;
    const size_t bh = (size_t)b * 16 + hv;
    u16(*buf)[66] = (u16(*)[66])sh;  // 128 x 66 = 8448 u16 <= 16384
    const int myhalf = wn >> 6;      // waves 0,1 -> d 0..63; waves 2,3 -> 64..127
#pragma unroll 1
    for (int half = 0; half < 2; ++half) {
      __syncthreads();
      if (myhalf == half) {
#pragma unroll
        for (int i = 0; i < 4; ++i)
#pragma unroll
          for (int j = 0; j < 4; ++j)
#pragma unroll
            for (int r = 0; r < 4; ++r)
              buf[wm + i * 16 + quad * 4 + r][j * 16 + lm] = f2b(acc[i][j][r]);
      }
      __syncthreads();
#pragma unroll
      for (int it = 0; it < 8; ++it) {
        const int idx = it * 256 + tid;
        const int dd = idx >> 5;    // 0..63
        const int sc4 = idx & 31;   // ushort4 index along s
        ushort4 v;
        v.x = buf[sc4 * 4 + 0][dd];
        v.y = buf[sc4 * 4 + 1][dd];
        v.z = buf[sc4 * 4 + 2][dd];
        v.w = buf[sc4 * 4 + 3][dd];
        *(ushort4*)(VT + (bh * 128 + half * 64 + dd) * 2048 + sbase + sc4 * 4) = v;
      }
    }
  }
}

// ---------------- fused causal attention v8 (R6-passed: XCD-affinity remap) ---
__global__ __launch_bounds__(256, 2) void attn_v8(const u16* __restrict__ Q,
                                                  const u16* __restrict__ K,
                                                  const u16* __restrict__ VT,
                                                  u16* __restrict__ O) {
  constexpr int S = 2048;
  constexpr int D = 128;
  __shared__ u16 Ks[2][64 * 128];  // chunk-swizzled
  __shared__ u16 Vs[2][128 * 64];  // VT tile [d][s_local], chunk-swizzled
  __shared__ u16 Ps[64 * 72];      // wave-private rows; padded stride 72
  const int linear = blockIdx.x + (blockIdx.y << 4);
  const int xcd = linear & 7;
  const int slot = linear >> 3;          // 0..63
  const int bh = (xcd << 2) + (slot >> 4);
  const int bx = slot & 15;
  const int b = bh >> 4, h = bh & 15;
  const int tid = threadIdx.x, wid = tid >> 6, lane = tid & 63;
  const int lm = lane & 15, quad = lane >> 4;
  const int rx = lm & 7;
  const int wrow = wid * 16;

  const u16* Kbh = K + (size_t)bh * S * D;
  const u16* Vbh = VT + (size_t)bh * D * S;

  auto stageKV = [&](int kt, int bufid) {
    const u16* Kt = Kbh + (size_t)kt * 64 * D;
    const u16* Vt = Vbh + (size_t)kt * 64;
#pragma unroll
    for (int it = 0; it < 4; ++it) {
      int c = it * 256 + tid;
      int row = c >> 4, u = c & 15;
      g2l16(Kt + (size_t)row * 128 + (size_t)(u ^ (row & 7)) * 8, &Ks[bufid][c * 8]);
    }
#pragma unroll
    for (int it = 0; it < 4; ++it) {
      int c = it * 256 + tid;
      int row = c >> 3, u = c & 7;
      g2l16(Vt + (size_t)row * S + (size_t)(u ^ (row & 7)) * 8, &Vs[bufid][c * 8]);
    }
  };

#pragma unroll 1
  for (int pass = 0; pass < 2; ++pass) {
    const int qt = pass == 0 ? bx : 31 - bx;

    bf16x8 aq[4];
#pragma unroll
    for (int ks = 0; ks < 4; ++ks)
      aq[ks] = *(const bf16x8*)(Q + ((size_t)bh * S + (size_t)qt * 64 + wrow + lm) * D +
                                ks * 32 + quad * 8);

    float l_r[4] = {0.f, 0.f, 0.f, 0.f};
    f32x4 zero = {0.f, 0.f, 0.f, 0.f};
    f32x4 oacc[8];
#pragma unroll
    for (int t = 0; t < 8; ++t) oacc[t] = zero;

    stageKV(0, 0);
    asm volatile("s_waitcnt vmcnt(0)" ::: "memory");
    __builtin_amdgcn_s_barrier();

#pragma unroll 1
    for (int kt = 0; kt <= qt; ++kt) {
      const int cur = kt & 1;
      if (kt < qt) stageKV(kt + 1, cur ^ 1);

      f32x4 sc[4];
#pragma unroll
      for (int j = 0; j < 4; ++j) sc[j] = zero;
      __builtin_amdgcn_s_setprio(1);
#pragma unroll
      for (int ks = 0; ks < 4; ++ks) {
        const int kc = ks * 4 + quad;
#pragma unroll
        for (int j = 0; j < 4; ++j) {
          bf16x8 bk = *(const bf16x8*)(&Ks[cur][((j * 16 + lm) * 16 + (kc ^ rx)) * 8]);
          sc[j] = MFMA32(aq[ks], bk, sc[j]);
        }
      }
      __builtin_amdgcn_s_setprio(0);

      const bool diag = (kt == qt);
#pragma unroll
      for (int r = 0; r < 4; ++r) {
        const int qcol = wrow + quad * 4 + r;
        float pv[4];
        float rs = 0.f;
#pragma unroll
        for (int j = 0; j < 4; ++j) {
          float p = __builtin_amdgcn_exp2f(fminf(sc[j][r], 30.0f));
          if (diag && (j * 16 + lm > qcol)) p = 0.f;
          rs += p;
          pv[j] = p;
        }
#pragma unroll
        for (int dd = 1; dd < 16; dd <<= 1) rs += __shfl_xor(rs, dd);
        l_r[r] += rs;
        const int prow = (wrow + quad * 4 + r) * 72;
#pragma unroll
        for (int j = 0; j < 4; ++j) Ps[prow + j * 16 + lm] = f2b(pv[j]);
      }

      __builtin_amdgcn_s_setprio(1);
#pragma unroll
      for (int ks = 0; ks < 2; ++ks) {
        bf16x8 ap = *(const bf16x8*)(Ps + (wrow + lm) * 72 + ks * 32 + quad * 8);
        const int kc = ks * 4 + quad;
#pragma unroll
        for (int t = 0; t < 8; ++t) {
          bf16x8 bv = *(const bf16x8*)(&Vs[cur][((t * 16 + lm) * 8 + (kc ^ rx)) * 8]);
          oacc[t] = MFMA32(ap, bv, oacc[t]);
        }
      }
      __builtin_amdgcn_s_setprio(0);

      if (kt < qt) asm volatile("s_waitcnt vmcnt(0)" ::: "memory");
      __builtin_amdgcn_s_barrier();
    }

#pragma unroll
    for (int r = 0; r < 4; ++r) {
      float inv = 1.0f / l_r[r];
      const int srow = qt * 64 + wrow + quad * 4 + r;
      u16* Orow = O + ((size_t)b * S + srow) * 2048 + h * 128;
#pragma unroll
      for (int t = 0; t < 8; ++t) Orow[t * 16 + lm] = f2b(oacc[t][r] * inv);
    }
  }
}

extern "C" void kernel_launch(void* const* d_in, const int* in_sizes, int n_in,
                              void* d_out, int out_size, void* d_ws, size_t ws_size,
                              hipStream_t stream) {
  const float* x      = (const float*)d_in[0];
  const float* Wq_sem = (const float*)d_in[1];
  const float* Wk_sem = (const float*)d_in[2];
  const float* Wq_geo = (const float*)d_in[3];
  const float* Wk_geo = (const float*)d_in[4];
  const float* Wv     = (const float*)d_in[5];
  const float* Wo     = (const float*)d_in[6];

  char* ws = (char*)d_ws;
  // layout (bytes):
  //   [0, 16M)          xb  (x bf16, 4096x2048)
  //   [16M, 41.2M)      Wall (6144x2048 bf16)   -> later reused as O
  //   [41.2M, 49.6M)    Wob  (2048x2048 bf16)
  //   [49.6M, 66.3M)    Qb   (bf16, 32 heads x 2048 x 128)  [Y slot freed by fusion]
  // d_out (33.5MB) used as scratch for K (16.7M) + VT (16.7M) until final GEMM.
  u16* xb   = (u16*)(ws);
  u16* Wall = (u16*)(ws + 16777216);
  u16* Wob  = (u16*)(ws + 16777216 + 25165824);
  u16* Qb   = (u16*)(ws + 16777216 + 25165824 + 8388608);
  u16* Ob   = Wall;
  u16* Kb   = (u16*)d_out;
  u16* VT   = (u16*)((char*)d_out + 16777216);

  // casts to bf16 (2 launches)
  cast_f2b_v4<<<8192, 256, 0, stream>>>(x, xb, 2097152);
  cast_weights<<<16384, 256, 0, stream>>>(Wq_sem, Wk_sem, Wq_geo, Wk_geo, Wv, Wo, Wall, Wob);

  // fused QKV projection + RoPE + head rearrange: writes Q/K/VT directly
  gemm_qkv<<<dim3(48, 32), 256, 0, stream>>>(xb, Wall, Qb, Kb, VT);

  // causal flash attention -> O (B*S, 2048) bf16
  attn_v8<<<dim3(16, 32), 256, 0, stream>>>(Qb, Kb, VT, Ob);

  // final projection: out = O @ Wo^T  (M=4096, N=2048, K=2048), fp32 out
  gemm_bt<false><<<dim3(16, 32), 256, 0, stream>>>(Ob, Wob, d_out, 2048, 2048);
}